// Round 16
// baseline (337.226 us; speedup 1.0000x reference)
//
#include <hip/hip_runtime.h>
#include <cmath>

#define TPB   128                 // threads per block (2 waves); each thread owns 4 cols
#define TH    16                  // output rows per block tile (22 input rows)
#define WID   512
#define HEI   512
#define NIMG  64
#define NTILE (HEI / TH)          // 32
#define NBLK  (NIMG * NTILE)      // 2048

// LEDGER: R14 = 50.1us floor (56 VGPR, VALUBusy 51%). Five forced-prefetch
// structures spilled (R2,R3,R9,R13,R15) at every launch_bounds cap
// (cap = 256/N for TPB=128). R16: BRANCHLESS stages — row index clamped
// (scalar s_max/s_min, gy wave-uniform), out-of-range rows zeroed via one
// pk-mul on the packed sd (sq=sd*sd auto-zeroes). Kernel body becomes one
// straight-line basic block so the machine scheduler may hoist next-stage
// loads by its own cost model (nothing forced). Cap (,3)=85 VGPR gives
// 29 regs of hoist headroom, balloon-limited.

typedef _Float16 h2 __attribute__((ext_vector_type(2)));

struct GW { unsigned int wh[7]; };   // f16 weight broadcast pairs (lo==hi), SGPR-resident

__device__ __forceinline__ h2 pkrtz(float a, float b) {
    return __builtin_bit_cast(h2, __builtin_amdgcn_cvt_pkrtz(a, b));
}
__device__ __forceinline__ h2 fma2(h2 a, h2 b, h2 c) { return __builtin_elementwise_fma(a, b, c); }

// One input-row stage, branchless: load clamped row, pack (s,d) per column
// (zeroed by vf if row out of range), H-blur into ring slot SL; when IY>=6
// V-blur the ring + SSIM accumulate (f32).
template <int SL, bool VB>
__device__ __forceinline__ void ssim_stage(
    int gy, int m, int c0, int clm, int clp,
    const float* __restrict__ pb, const float* __restrict__ tb,
    const h2 (&w2)[7],
    h2 (&rAB)[7][4], h2 (&rST)[7][4],
    float& acc)
{
    // wave-uniform row clamp + validity factor (scalar ops, no branch)
    const int gyc = gy < 0 ? 0 : (gy > HEI - 1 ? HEI - 1 : gy);
    const float vf = (gy >= 0 && gy < HEI) ? 1.0f : 0.0f;
    const h2 vh = pkrtz(vf, vf);

    const float* pr = pb + (size_t)gyc * WID;
    const float* tr = tb + (size_t)gyc * WID;
    float4 v0 = *(const float4*)(pr + clm);
    float4 v1 = *(const float4*)(pr + c0);
    float4 v2 = *(const float4*)(pr + clp);
    float4 u0 = *(const float4*)(tr + clm);
    float4 u1 = *(const float4*)(tr + c0);
    float4 u2 = *(const float4*)(tr + clp);
    if (m == 0)       { v0 = make_float4(0.f,0.f,0.f,0.f); u0 = make_float4(0.f,0.f,0.f,0.f); }
    if (m == TPB - 1) { v2 = make_float4(0.f,0.f,0.f,0.f); u2 = make_float4(0.f,0.f,0.f,0.f); }

    float pa[12], ta[12];
    pa[0]=v0.x; pa[1]=v0.y; pa[2]=v0.z; pa[3]=v0.w;
    pa[4]=v1.x; pa[5]=v1.y; pa[6]=v1.z; pa[7]=v1.w;
    pa[8]=v2.x; pa[9]=v2.y; pa[10]=v2.z; pa[11]=v2.w;
    ta[0]=u0.x; ta[1]=u0.y; ta[2]=u0.z; ta[3]=u0.w;
    ta[4]=u1.x; ta[5]=u1.y; ta[6]=u1.z; ta[7]=u1.w;
    ta[8]=u2.x; ta[9]=u2.y; ta[10]=u2.z; ta[11]=u2.w;

    // window col k = image column (c0 - 3 + k); output col c uses k = c..c+6
    h2 sd[10], sq[10];
#pragma unroll
    for (int k = 0; k < 10; ++k) {
        const float s = pa[k + 1] + ta[k + 1];
        const float d = pa[k + 1] - ta[k + 1];
        sd[k] = pkrtz(s, d) * vh;   // (s,d) packed; zeroed when row invalid
        sq[k] = sd[k] * sd[k];      // (s^2, d^2) auto-zeroed
    }

    // H-blur both packed fields: 4 cols x 7 taps pk-fma each
#pragma unroll
    for (int c = 0; c < 4; ++c) {
        h2 ab = w2[0] * sd[c];
        h2 st = w2[0] * sq[c];
#pragma unroll
        for (int i = 1; i < 7; ++i) {
            ab = fma2(w2[i], sd[c + i], ab);
            st = fma2(w2[i], sq[c + i], st);
        }
        rAB[SL][c] = ab;
        rST[SL][c] = st;
    }

    if constexpr (VB) {
        const float C1 = 1e-4f, C2 = 9e-4f;
#pragma unroll
        for (int c = 0; c < 4; ++c) {
            h2 vAB = w2[0] * rAB[(SL + 1) % 7][c];
            h2 vST = w2[0] * rST[(SL + 1) % 7][c];
#pragma unroll
            for (int j = 1; j < 7; ++j) {
                const int sl = (SL + 1 + j) % 7;   // compile-time
                vAB = fma2(w2[j], rAB[sl][c], vAB);
                vST = fma2(w2[j], rST[sl][c], vST);
            }
            const float fA = (float)vAB[0], fB = (float)vAB[1];
            const float fS = (float)vST[0], fT = (float)vST[1];
            const float A2 = fA * fA, B2 = fB * fB;
            const float muct2 = 0.5f * (A2 - B2);   // 2*mu_p*mu_t
            const float muss  = 0.5f * (A2 + B2);   // mu_p^2 + mu_t^2
            const float ptb2  = 0.5f * (fS - fT);   // 2*blur(p*t)
            const float ssb   = 0.5f * (fS + fT);   // blur(p^2 + t^2)
            const float num = (muct2 + C1) * (ptb2 - muct2 + C2);
            const float den = (muss + C1) * (ssb - muss + C2);
            acc += num * __builtin_amdgcn_rcpf(den);
        }
    }
}

__global__ __launch_bounds__(TPB, 3)
void ssim_main_k(const float* __restrict__ pred,
                 const float* __restrict__ targ,
                 float* __restrict__ partial,   // NBLK floats (d_ws), or null
                 float* __restrict__ outacc,    // fallback atomic accumulator
                 GW gw)
{
    const int m    = threadIdx.x;
    const int bid  = blockIdx.x;
    const int img  = bid >> 5;            // NTILE == 32
    const int tile = bid & (NTILE - 1);
    const int oy0  = tile * TH;

    h2 w2[7];
#pragma unroll
    for (int j = 0; j < 7; ++j) w2[j] = __builtin_bit_cast(h2, gw.wh[j]);

    const size_t ioff = (size_t)img * (WID * HEI);
    const float* pb = pred + ioff;
    const float* tb = targ + ioff;

    const int c0  = 4 * m;
    const int clm = (m == 0) ? 0 : (c0 - 4);          // clamped (value zeroed)
    const int clp = (m == TPB - 1) ? c0 : (c0 + 4);   // clamped (value zeroed)

    h2 rAB[7][4], rST[7][4];    // ring: [slot][col], (A,B) and (S,T) packed
    float acc = 0.f;
    const int g0 = oy0 - 3;

    // 22 input rows, fully unrolled, straight-line (no branches)
    ssim_stage<0, false>(g0 +  0, m, c0, clm, clp, pb, tb, w2, rAB, rST, acc);
    ssim_stage<1, false>(g0 +  1, m, c0, clm, clp, pb, tb, w2, rAB, rST, acc);
    ssim_stage<2, false>(g0 +  2, m, c0, clm, clp, pb, tb, w2, rAB, rST, acc);
    ssim_stage<3, false>(g0 +  3, m, c0, clm, clp, pb, tb, w2, rAB, rST, acc);
    ssim_stage<4, false>(g0 +  4, m, c0, clm, clp, pb, tb, w2, rAB, rST, acc);
    ssim_stage<5, false>(g0 +  5, m, c0, clm, clp, pb, tb, w2, rAB, rST, acc);
    ssim_stage<6, true >(g0 +  6, m, c0, clm, clp, pb, tb, w2, rAB, rST, acc);
    ssim_stage<0, true >(g0 +  7, m, c0, clm, clp, pb, tb, w2, rAB, rST, acc);
    ssim_stage<1, true >(g0 +  8, m, c0, clm, clp, pb, tb, w2, rAB, rST, acc);
    ssim_stage<2, true >(g0 +  9, m, c0, clm, clp, pb, tb, w2, rAB, rST, acc);
    ssim_stage<3, true >(g0 + 10, m, c0, clm, clp, pb, tb, w2, rAB, rST, acc);
    ssim_stage<4, true >(g0 + 11, m, c0, clm, clp, pb, tb, w2, rAB, rST, acc);
    ssim_stage<5, true >(g0 + 12, m, c0, clm, clp, pb, tb, w2, rAB, rST, acc);
    ssim_stage<6, true >(g0 + 13, m, c0, clm, clp, pb, tb, w2, rAB, rST, acc);
    ssim_stage<0, true >(g0 + 14, m, c0, clm, clp, pb, tb, w2, rAB, rST, acc);
    ssim_stage<1, true >(g0 + 15, m, c0, clm, clp, pb, tb, w2, rAB, rST, acc);
    ssim_stage<2, true >(g0 + 16, m, c0, clm, clp, pb, tb, w2, rAB, rST, acc);
    ssim_stage<3, true >(g0 + 17, m, c0, clm, clp, pb, tb, w2, rAB, rST, acc);
    ssim_stage<4, true >(g0 + 18, m, c0, clm, clp, pb, tb, w2, rAB, rST, acc);
    ssim_stage<5, true >(g0 + 19, m, c0, clm, clp, pb, tb, w2, rAB, rST, acc);
    ssim_stage<6, true >(g0 + 20, m, c0, clm, clp, pb, tb, w2, rAB, rST, acc);
    ssim_stage<0, true >(g0 + 21, m, c0, clm, clp, pb, tb, w2, rAB, rST, acc);

    // block reduction: wave shfl tree, then cross-wave via LDS
#pragma unroll
    for (int off = 32; off > 0; off >>= 1)
        acc += __shfl_down(acc, off, 64);
    __shared__ float wpart[TPB / 64];
    if ((m & 63) == 0) wpart[m >> 6] = acc;
    __syncthreads();
    if (m == 0) {
        const float tot = wpart[0] + wpart[1];
        if (partial) partial[bid] = tot;
        else atomicAdd(outacc, tot);
    }
}

__global__ void ssim_finalize_k(const float* __restrict__ partial,
                                float* __restrict__ out, int usews)
{
    const float invN = 1.0f / (float)((size_t)NIMG * WID * HEI);
    if (usews) {
        float s = 0.f;
        for (int i = threadIdx.x; i < NBLK; i += 256) s += partial[i];
#pragma unroll
        for (int off = 32; off > 0; off >>= 1) s += __shfl_down(s, off, 64);
        __shared__ float wp[4];
        if ((threadIdx.x & 63) == 0) wp[threadIdx.x >> 6] = s;
        __syncthreads();
        if (threadIdx.x == 0) out[0] = 1.0f - (wp[0] + wp[1] + wp[2] + wp[3]) * invN;
    } else {
        if (threadIdx.x == 0) out[0] = 1.0f - out[0] * invN;
    }
}

// host f32 -> f16 bits, round-to-nearest-even (weights are normal, positive)
static unsigned short f32_to_f16(float f) {
    union { float f; unsigned int u; } c; c.f = f;
    const unsigned int u = c.u;
    const int exp = (int)((u >> 23) & 0xFF) - 127 + 15;
    const unsigned int man = u & 0x7FFFFFu;
    if (exp <= 0) return 0;
    unsigned int base = ((unsigned int)exp << 10) | (man >> 13);
    const unsigned int rem = man & 0x1FFFu;
    base += (rem > 0x1000u) || (rem == 0x1000u && (base & 1u));
    return (unsigned short)base;
}
static float f16_to_f32(unsigned short h) {
    const int exp = (h >> 10) & 0x1F;
    const unsigned int man = h & 0x3FFu;
    if (exp == 0) return 0.f;
    union { unsigned int u; float f; } c;
    c.u = ((unsigned int)(exp - 15 + 127) << 23) | (man << 13);
    return c.f;
}

extern "C" void kernel_launch(void* const* d_in, const int* in_sizes, int n_in,
                              void* d_out, int out_size, void* d_ws, size_t ws_size,
                              hipStream_t stream)
{
    const float* pred = (const float*)d_in[0];
    const float* targ = (const float*)d_in[1];
    float* out = (float*)d_out;

    GW gw;
    {
        double g[7], s = 0.0;
        for (int i = 0; i < 7; ++i) {
            const double c = (double)(i - 3);
            g[i] = exp(-c * c / (2.0 * 1.5 * 1.5));
            s += g[i];
        }
        unsigned short h16[7];
        for (int i = 0; i < 7; ++i) h16[i] = f32_to_f16((float)(g[i] / s));
        // renormalize so the f16 weights sum as close to 1.0 as representable:
        // center tap = round_f16(1 - sum(others)) kills the systematic bias.
        float so = 0.f;
        for (int i = 0; i < 7; ++i) if (i != 3) so += f16_to_f32(h16[i]);
        h16[3] = f32_to_f16(1.0f - so);
        for (int i = 0; i < 7; ++i)
            gw.wh[i] = (unsigned int)h16[i] | ((unsigned int)h16[i] << 16);
    }

    const bool usews = (ws_size >= NBLK * sizeof(float));
    float* partial = usews ? (float*)d_ws : nullptr;
    if (!usews) (void)hipMemsetAsync(d_out, 0, sizeof(float), stream);

    ssim_main_k<<<NBLK, TPB, 0, stream>>>(pred, targ, partial, out, gw);
    ssim_finalize_k<<<1, 256, 0, stream>>>(partial, out, usews ? 1 : 0);
}

// Round 17
// 192.269 us; speedup vs baseline: 1.7539x; 1.7539x over previous
//
#include <hip/hip_runtime.h>
#include <cmath>

#define TPB   128                 // threads per block (2 waves); each thread owns 4 cols
#define TH    16                  // output rows per block tile (22 input rows)
#define WID   512
#define HEI   512
#define NIMG  64
#define NTILE (HEI / TH)          // 32
#define NBLK  (NIMG * NTILE)      // 2048

// LEDGER: R14 = 50.1us (56 VGPR, VALUBusy 51%, branchy stages = implicit
// scheduler fences = exposed load latency). Forced prefetch spills
// (R2,R3,R9,R13,R15). Fully branchless spills (R16: scheduler hoists
// unbounded, 84=cap VGPR + 508MB scratch). R17 = bounded fence design:
//  (a) branchless clamped loads (stage internally one block),
//  (b) V-blur phase-shifted to BEFORE load consumption (independent of
//      this stage's loads -> ~170cy of free latency coverage),
//  (c) __builtin_amdgcn_sched_barrier(0) at each stage boundary (hoist
//      capped at one stage's footprint ~105 regs < 128 cap).

typedef _Float16 h2 __attribute__((ext_vector_type(2)));

struct GW { unsigned int wh[7]; };   // f16 weight broadcast pairs (lo==hi), SGPR-resident

__device__ __forceinline__ h2 pkrtz(float a, float b) {
    return __builtin_bit_cast(h2, __builtin_amdgcn_cvt_pkrtz(a, b));
}
__device__ __forceinline__ h2 fma2(h2 a, h2 b, h2 c) { return __builtin_elementwise_fma(a, b, c); }

// One stage. LD: issue clamped loads for row gy, then (VB) V-blur the window
// ENDING at row gy-1 (ring-only, independent of the loads), then consume the
// loads: pack (s,d)*vf, H-blur into slot SL. VB output row = gy-4.
template <int SL, bool LD, bool VB>
__device__ __forceinline__ void ssim_stage(
    int gy, int m, int c0, int clm, int clp,
    const float* __restrict__ pb, const float* __restrict__ tb,
    const h2 (&w2)[7],
    h2 (&rAB)[7][4], h2 (&rST)[7][4],
    float& acc)
{
    float4 v0, v1, v2, u0, u1, u2;
    h2 vh;
    if constexpr (LD) {
        // wave-uniform clamp + validity factor (branchless)
        const int gyc = gy < 0 ? 0 : (gy > HEI - 1 ? HEI - 1 : gy);
        const float vf = (gy >= 0 && gy < HEI) ? 1.0f : 0.0f;
        vh = pkrtz(vf, vf);
        const float* pr = pb + (size_t)gyc * WID;
        const float* tr = tb + (size_t)gyc * WID;
        v0 = *(const float4*)(pr + clm);
        v1 = *(const float4*)(pr + c0);
        v2 = *(const float4*)(pr + clp);
        u0 = *(const float4*)(tr + clm);
        u1 = *(const float4*)(tr + c0);
        u2 = *(const float4*)(tr + clp);
        if (m == 0)       { v0 = make_float4(0.f,0.f,0.f,0.f); u0 = make_float4(0.f,0.f,0.f,0.f); }
        if (m == TPB - 1) { v2 = make_float4(0.f,0.f,0.f,0.f); u2 = make_float4(0.f,0.f,0.f,0.f); }
    }

    if constexpr (VB) {
        // window rows gy-7..gy-1; row gy-7+j lives in slot (SL+j)%7, weight w[j]
        const float C1 = 1e-4f, C2 = 9e-4f;
#pragma unroll
        for (int c = 0; c < 4; ++c) {
            h2 vAB = w2[0] * rAB[SL][c];
            h2 vST = w2[0] * rST[SL][c];
#pragma unroll
            for (int j = 1; j < 7; ++j) {
                const int sl = (SL + j) % 7;   // compile-time
                vAB = fma2(w2[j], rAB[sl][c], vAB);
                vST = fma2(w2[j], rST[sl][c], vST);
            }
            const float fA = (float)vAB[0], fB = (float)vAB[1];
            const float fS = (float)vST[0], fT = (float)vST[1];
            const float A2 = fA * fA, B2 = fB * fB;
            const float muct2 = 0.5f * (A2 - B2);   // 2*mu_p*mu_t
            const float muss  = 0.5f * (A2 + B2);   // mu_p^2 + mu_t^2
            const float ptb2  = 0.5f * (fS - fT);   // 2*blur(p*t)
            const float ssb   = 0.5f * (fS + fT);   // blur(p^2 + t^2)
            const float num = (muct2 + C1) * (ptb2 - muct2 + C2);
            const float den = (muss + C1) * (ssb - muss + C2);
            acc += num * __builtin_amdgcn_rcpf(den);
        }
    }

    if constexpr (LD) {
        float pa[12], ta[12];
        pa[0]=v0.x; pa[1]=v0.y; pa[2]=v0.z; pa[3]=v0.w;
        pa[4]=v1.x; pa[5]=v1.y; pa[6]=v1.z; pa[7]=v1.w;
        pa[8]=v2.x; pa[9]=v2.y; pa[10]=v2.z; pa[11]=v2.w;
        ta[0]=u0.x; ta[1]=u0.y; ta[2]=u0.z; ta[3]=u0.w;
        ta[4]=u1.x; ta[5]=u1.y; ta[6]=u1.z; ta[7]=u1.w;
        ta[8]=u2.x; ta[9]=u2.y; ta[10]=u2.z; ta[11]=u2.w;

        // window col k = image column (c0 - 3 + k); output col c uses k = c..c+6
        h2 sd[10], sq[10];
#pragma unroll
        for (int k = 0; k < 10; ++k) {
            const float s = pa[k + 1] + ta[k + 1];
            const float d = pa[k + 1] - ta[k + 1];
            sd[k] = pkrtz(s, d) * vh;   // zeroed when row out of range
            sq[k] = sd[k] * sd[k];
        }
#pragma unroll
        for (int c = 0; c < 4; ++c) {
            h2 ab = w2[0] * sd[c];
            h2 st = w2[0] * sq[c];
#pragma unroll
            for (int i = 1; i < 7; ++i) {
                ab = fma2(w2[i], sd[c + i], ab);
                st = fma2(w2[i], sq[c + i], st);
            }
            rAB[SL][c] = ab;
            rST[SL][c] = st;
        }
    }

    __builtin_amdgcn_sched_barrier(0);   // bound hoisting to one stage
}

__global__ __launch_bounds__(TPB, 2)
void ssim_main_k(const float* __restrict__ pred,
                 const float* __restrict__ targ,
                 float* __restrict__ partial,   // NBLK floats (d_ws), or null
                 float* __restrict__ outacc,    // fallback atomic accumulator
                 GW gw)
{
    const int m    = threadIdx.x;
    const int bid  = blockIdx.x;
    const int img  = bid >> 5;            // NTILE == 32
    const int tile = bid & (NTILE - 1);
    const int oy0  = tile * TH;

    h2 w2[7];
#pragma unroll
    for (int j = 0; j < 7; ++j) w2[j] = __builtin_bit_cast(h2, gw.wh[j]);

    const size_t ioff = (size_t)img * (WID * HEI);
    const float* pb = pred + ioff;
    const float* tb = targ + ioff;

    const int c0  = 4 * m;
    const int clm = (m == 0) ? 0 : (c0 - 4);          // clamped (value zeroed)
    const int clp = (m == TPB - 1) ? c0 : (c0 + 4);   // clamped (value zeroed)

    h2 rAB[7][4], rST[7][4];    // ring: [slot][col], (A,B) and (S,T) packed
    float acc = 0.f;
    const int g0 = oy0 - 3;

    // 23 stages: IY=0..21 load row g0+IY (slot IY%7); IY>=7 also V-blur the
    // window ending at row g0+IY-1 (output row oy0+IY-7); IY=22 V-blur only.
    ssim_stage<0, true,  false>(g0 +  0, m, c0, clm, clp, pb, tb, w2, rAB, rST, acc);
    ssim_stage<1, true,  false>(g0 +  1, m, c0, clm, clp, pb, tb, w2, rAB, rST, acc);
    ssim_stage<2, true,  false>(g0 +  2, m, c0, clm, clp, pb, tb, w2, rAB, rST, acc);
    ssim_stage<3, true,  false>(g0 +  3, m, c0, clm, clp, pb, tb, w2, rAB, rST, acc);
    ssim_stage<4, true,  false>(g0 +  4, m, c0, clm, clp, pb, tb, w2, rAB, rST, acc);
    ssim_stage<5, true,  false>(g0 +  5, m, c0, clm, clp, pb, tb, w2, rAB, rST, acc);
    ssim_stage<6, true,  false>(g0 +  6, m, c0, clm, clp, pb, tb, w2, rAB, rST, acc);
    ssim_stage<0, true,  true >(g0 +  7, m, c0, clm, clp, pb, tb, w2, rAB, rST, acc);
    ssim_stage<1, true,  true >(g0 +  8, m, c0, clm, clp, pb, tb, w2, rAB, rST, acc);
    ssim_stage<2, true,  true >(g0 +  9, m, c0, clm, clp, pb, tb, w2, rAB, rST, acc);
    ssim_stage<3, true,  true >(g0 + 10, m, c0, clm, clp, pb, tb, w2, rAB, rST, acc);
    ssim_stage<4, true,  true >(g0 + 11, m, c0, clm, clp, pb, tb, w2, rAB, rST, acc);
    ssim_stage<5, true,  true >(g0 + 12, m, c0, clm, clp, pb, tb, w2, rAB, rST, acc);
    ssim_stage<6, true,  true >(g0 + 13, m, c0, clm, clp, pb, tb, w2, rAB, rST, acc);
    ssim_stage<0, true,  true >(g0 + 14, m, c0, clm, clp, pb, tb, w2, rAB, rST, acc);
    ssim_stage<1, true,  true >(g0 + 15, m, c0, clm, clp, pb, tb, w2, rAB, rST, acc);
    ssim_stage<2, true,  true >(g0 + 16, m, c0, clm, clp, pb, tb, w2, rAB, rST, acc);
    ssim_stage<3, true,  true >(g0 + 17, m, c0, clm, clp, pb, tb, w2, rAB, rST, acc);
    ssim_stage<4, true,  true >(g0 + 18, m, c0, clm, clp, pb, tb, w2, rAB, rST, acc);
    ssim_stage<5, true,  true >(g0 + 19, m, c0, clm, clp, pb, tb, w2, rAB, rST, acc);
    ssim_stage<6, true,  true >(g0 + 20, m, c0, clm, clp, pb, tb, w2, rAB, rST, acc);
    ssim_stage<0, true,  true >(g0 + 21, m, c0, clm, clp, pb, tb, w2, rAB, rST, acc);
    ssim_stage<1, false, true >(g0 + 22, m, c0, clm, clp, pb, tb, w2, rAB, rST, acc);

    // block reduction: wave shfl tree, then cross-wave via LDS
#pragma unroll
    for (int off = 32; off > 0; off >>= 1)
        acc += __shfl_down(acc, off, 64);
    __shared__ float wpart[TPB / 64];
    if ((m & 63) == 0) wpart[m >> 6] = acc;
    __syncthreads();
    if (m == 0) {
        const float tot = wpart[0] + wpart[1];
        if (partial) partial[bid] = tot;
        else atomicAdd(outacc, tot);
    }
}

__global__ void ssim_finalize_k(const float* __restrict__ partial,
                                float* __restrict__ out, int usews)
{
    const float invN = 1.0f / (float)((size_t)NIMG * WID * HEI);
    if (usews) {
        float s = 0.f;
        for (int i = threadIdx.x; i < NBLK; i += 256) s += partial[i];
#pragma unroll
        for (int off = 32; off > 0; off >>= 1) s += __shfl_down(s, off, 64);
        __shared__ float wp[4];
        if ((threadIdx.x & 63) == 0) wp[threadIdx.x >> 6] = s;
        __syncthreads();
        if (threadIdx.x == 0) out[0] = 1.0f - (wp[0] + wp[1] + wp[2] + wp[3]) * invN;
    } else {
        if (threadIdx.x == 0) out[0] = 1.0f - out[0] * invN;
    }
}

// host f32 -> f16 bits, round-to-nearest-even (weights are normal, positive)
static unsigned short f32_to_f16(float f) {
    union { float f; unsigned int u; } c; c.f = f;
    const unsigned int u = c.u;
    const int exp = (int)((u >> 23) & 0xFF) - 127 + 15;
    const unsigned int man = u & 0x7FFFFFu;
    if (exp <= 0) return 0;
    unsigned int base = ((unsigned int)exp << 10) | (man >> 13);
    const unsigned int rem = man & 0x1FFFu;
    base += (rem > 0x1000u) || (rem == 0x1000u && (base & 1u));
    return (unsigned short)base;
}
static float f16_to_f32(unsigned short h) {
    const int exp = (h >> 10) & 0x1F;
    const unsigned int man = h & 0x3FFu;
    if (exp == 0) return 0.f;
    union { unsigned int u; float f; } c;
    c.u = ((unsigned int)(exp - 15 + 127) << 23) | (man << 13);
    return c.f;
}

extern "C" void kernel_launch(void* const* d_in, const int* in_sizes, int n_in,
                              void* d_out, int out_size, void* d_ws, size_t ws_size,
                              hipStream_t stream)
{
    const float* pred = (const float*)d_in[0];
    const float* targ = (const float*)d_in[1];
    float* out = (float*)d_out;

    GW gw;
    {
        double g[7], s = 0.0;
        for (int i = 0; i < 7; ++i) {
            const double c = (double)(i - 3);
            g[i] = exp(-c * c / (2.0 * 1.5 * 1.5));
            s += g[i];
        }
        unsigned short h16[7];
        for (int i = 0; i < 7; ++i) h16[i] = f32_to_f16((float)(g[i] / s));
        // renormalize so the f16 weights sum as close to 1.0 as representable:
        // center tap = round_f16(1 - sum(others)) kills the systematic bias.
        float so = 0.f;
        for (int i = 0; i < 7; ++i) if (i != 3) so += f16_to_f32(h16[i]);
        h16[3] = f32_to_f16(1.0f - so);
        for (int i = 0; i < 7; ++i)
            gw.wh[i] = (unsigned int)h16[i] | ((unsigned int)h16[i] << 16);
    }

    const bool usews = (ws_size >= NBLK * sizeof(float));
    float* partial = usews ? (float*)d_ws : nullptr;
    if (!usews) (void)hipMemsetAsync(d_out, 0, sizeof(float), stream);

    ssim_main_k<<<NBLK, TPB, 0, stream>>>(pred, targ, partial, out, gw);
    ssim_finalize_k<<<1, 256, 0, stream>>>(partial, out, usews ? 1 : 0);
}

// Round 19
// 52.980 us; speedup vs baseline: 6.3652x; 3.6291x over previous
//
#include <hip/hip_runtime.h>
#include <cmath>

#define TPB    64                 // ONE wave per block; each thread owns 4 cols
#define TH     16                 // output rows per block tile (22 input rows)
#define CW     256                // columns per block strip = TPB*4  (R18 bug: was 128)
#define WID    512
#define HEI    512
#define NIMG   64
#define NTILE  (HEI / TH)         // 32
#define NSTRIP (WID / CW)         // 2
#define NBLK   (NIMG * NTILE * NSTRIP)   // 4096

// LEDGER: R14 = 50.1us floor shape (56 VGPR). Seven ILP structures spilled
// (R2,R3,R9,R13,R15,R16,R17). R18 strip-split crashed: 64 thr x 4 cols =
// 256 cols, not CW=128 -> OOB. R19 = corrected geometry: CW=256, 2 strips,
// 4096 single-wave blocks (same wave count as R14, finer granularity, no
// block-level reduction barrier, halo from neighbor strip is real data).
// Address audit: c0 in {0..252}u{256..508}; clm>=0, clp<=508, max col 511.

typedef _Float16 h2 __attribute__((ext_vector_type(2)));

struct GW { unsigned int wh[7]; };   // f16 weight broadcast pairs (lo==hi), SGPR-resident

__device__ __forceinline__ h2 pkrtz(float a, float b) {
    return __builtin_bit_cast(h2, __builtin_amdgcn_cvt_pkrtz(a, b));
}
__device__ __forceinline__ h2 fma2(h2 a, h2 b, h2 c) { return __builtin_elementwise_fma(a, b, c); }

// One input-row stage: load row gy (f32), pack (s,d)=(p+t,p-t) per column,
// H-blur both packed fields into ring slot SL; when IY>=6 V-blur + SSIM.
// zl/zr: thread sits at the true image left/right edge (zero the halo).
template <int SL>
__device__ __forceinline__ void ssim_stage(
    int IY, int oy0, bool zl, bool zr, int c0, int clm, int clp,
    const float* __restrict__ pb, const float* __restrict__ tb,
    const h2 (&w2)[7],
    h2 (&rAB)[7][4], h2 (&rST)[7][4],
    float& acc)
{
    const int gy = oy0 - 3 + IY;
    float pa[12], ta[12];
    if (gy >= 0 && gy < HEI) {
        const float* pr = pb + (size_t)gy * WID;
        const float* tr = tb + (size_t)gy * WID;
        float4 v0 = *(const float4*)(pr + clm);
        float4 v1 = *(const float4*)(pr + c0);
        float4 v2 = *(const float4*)(pr + clp);
        float4 u0 = *(const float4*)(tr + clm);
        float4 u1 = *(const float4*)(tr + c0);
        float4 u2 = *(const float4*)(tr + clp);
        if (zl) { v0 = make_float4(0.f,0.f,0.f,0.f); u0 = make_float4(0.f,0.f,0.f,0.f); }
        if (zr) { v2 = make_float4(0.f,0.f,0.f,0.f); u2 = make_float4(0.f,0.f,0.f,0.f); }
        pa[0]=v0.x; pa[1]=v0.y; pa[2]=v0.z; pa[3]=v0.w;
        pa[4]=v1.x; pa[5]=v1.y; pa[6]=v1.z; pa[7]=v1.w;
        pa[8]=v2.x; pa[9]=v2.y; pa[10]=v2.z; pa[11]=v2.w;
        ta[0]=u0.x; ta[1]=u0.y; ta[2]=u0.z; ta[3]=u0.w;
        ta[4]=u1.x; ta[5]=u1.y; ta[6]=u1.z; ta[7]=u1.w;
        ta[8]=u2.x; ta[9]=u2.y; ta[10]=u2.z; ta[11]=u2.w;
    } else {
#pragma unroll
        for (int k = 0; k < 12; ++k) { pa[k] = 0.f; ta[k] = 0.f; }
    }

    // window col k = image column (c0 - 3 + k); output col c uses k = c..c+6
    h2 sd[10], sq[10];
#pragma unroll
    for (int k = 0; k < 10; ++k) {
        const float s = pa[k + 1] + ta[k + 1];
        const float d = pa[k + 1] - ta[k + 1];
        sd[k] = pkrtz(s, d);        // (s, d) packed per column
        sq[k] = sd[k] * sd[k];      // (s^2, d^2)
    }

    // H-blur both packed fields: 4 cols x 7 taps pk-fma each
#pragma unroll
    for (int c = 0; c < 4; ++c) {
        h2 ab = w2[0] * sd[c];
        h2 st = w2[0] * sq[c];
#pragma unroll
        for (int i = 1; i < 7; ++i) {
            ab = fma2(w2[i], sd[c + i], ab);
            st = fma2(w2[i], sq[c + i], st);
        }
        rAB[SL][c] = ab;
        rST[SL][c] = st;
    }

    if (IY >= 6) {
        const float C1 = 1e-4f, C2 = 9e-4f;
#pragma unroll
        for (int c = 0; c < 4; ++c) {
            h2 vAB = w2[0] * rAB[(SL + 1) % 7][c];
            h2 vST = w2[0] * rST[(SL + 1) % 7][c];
#pragma unroll
            for (int j = 1; j < 7; ++j) {
                const int sl = (SL + 1 + j) % 7;   // compile-time
                vAB = fma2(w2[j], rAB[sl][c], vAB);
                vST = fma2(w2[j], rST[sl][c], vST);
            }
            const float fA = (float)vAB[0], fB = (float)vAB[1];
            const float fS = (float)vST[0], fT = (float)vST[1];
            const float A2 = fA * fA, B2 = fB * fB;
            const float muct2 = 0.5f * (A2 - B2);   // 2*mu_p*mu_t
            const float muss  = 0.5f * (A2 + B2);   // mu_p^2 + mu_t^2
            const float ptb2  = 0.5f * (fS - fT);   // 2*blur(p*t)
            const float ssb   = 0.5f * (fS + fT);   // blur(p^2 + t^2)
            const float num = (muct2 + C1) * (ptb2 - muct2 + C2);
            const float den = (muss + C1) * (ssb - muss + C2);
            acc += num * __builtin_amdgcn_rcpf(den);
        }
    }
}

__global__ __launch_bounds__(TPB, 4)
void ssim_main_k(const float* __restrict__ pred,
                 const float* __restrict__ targ,
                 float* __restrict__ partial,   // NBLK floats (d_ws), or null
                 float* __restrict__ outacc,    // fallback atomic accumulator
                 GW gw)
{
    const int m     = threadIdx.x;          // 0..63
    const int bid   = blockIdx.x;
    const int img   = bid >> 6;             // NTILE*NSTRIP == 64
    const int tile  = (bid >> 1) & (NTILE - 1);
    const int strip = bid & (NSTRIP - 1);
    const int oy0   = tile * TH;

    h2 w2[7];
#pragma unroll
    for (int j = 0; j < 7; ++j) w2[j] = __builtin_bit_cast(h2, gw.wh[j]);

    const size_t ioff = (size_t)img * (WID * HEI);
    const float* pb = pred + ioff;
    const float* tb = targ + ioff;

    const int  c0  = strip * CW + 4 * m;    // {0..252} or {256..508}
    const bool zl  = (c0 == 0);             // true image left edge
    const bool zr  = (c0 == WID - 4);       // true image right edge
    const int  clm = zl ? c0 : (c0 - 4);    // halo from neighbor strip otherwise
    const int  clp = zr ? c0 : (c0 + 4);

    h2 rAB[7][4], rST[7][4];    // ring: [slot][col], (A,B) and (S,T) packed
    float acc = 0.f;

    // 22 input rows = 3*7 + 1; groups of 7 so ring slot == IY % 7 is static
    for (int it = 0; it < 3; ++it) {
        const int base = it * 7;
        ssim_stage<0>(base + 0, oy0, zl, zr, c0, clm, clp, pb, tb, w2, rAB, rST, acc);
        ssim_stage<1>(base + 1, oy0, zl, zr, c0, clm, clp, pb, tb, w2, rAB, rST, acc);
        ssim_stage<2>(base + 2, oy0, zl, zr, c0, clm, clp, pb, tb, w2, rAB, rST, acc);
        ssim_stage<3>(base + 3, oy0, zl, zr, c0, clm, clp, pb, tb, w2, rAB, rST, acc);
        ssim_stage<4>(base + 4, oy0, zl, zr, c0, clm, clp, pb, tb, w2, rAB, rST, acc);
        ssim_stage<5>(base + 5, oy0, zl, zr, c0, clm, clp, pb, tb, w2, rAB, rST, acc);
        ssim_stage<6>(base + 6, oy0, zl, zr, c0, clm, clp, pb, tb, w2, rAB, rST, acc);
    }
    ssim_stage<0>(21, oy0, zl, zr, c0, clm, clp, pb, tb, w2, rAB, rST, acc);

    // single-wave block: pure shuffle reduction, lane 0 writes
#pragma unroll
    for (int off = 32; off > 0; off >>= 1)
        acc += __shfl_down(acc, off, 64);
    if (m == 0) {
        if (partial) partial[bid] = acc;
        else atomicAdd(outacc, acc);
    }
}

__global__ void ssim_finalize_k(const float* __restrict__ partial,
                                float* __restrict__ out, int usews)
{
    const float invN = 1.0f / (float)((size_t)NIMG * WID * HEI);
    if (usews) {
        float s = 0.f;
        for (int i = threadIdx.x; i < NBLK; i += 256) s += partial[i];
#pragma unroll
        for (int off = 32; off > 0; off >>= 1) s += __shfl_down(s, off, 64);
        __shared__ float wp[4];
        if ((threadIdx.x & 63) == 0) wp[threadIdx.x >> 6] = s;
        __syncthreads();
        if (threadIdx.x == 0) out[0] = 1.0f - (wp[0] + wp[1] + wp[2] + wp[3]) * invN;
    } else {
        if (threadIdx.x == 0) out[0] = 1.0f - out[0] * invN;
    }
}

// host f32 -> f16 bits, round-to-nearest-even (weights are normal, positive)
static unsigned short f32_to_f16(float f) {
    union { float f; unsigned int u; } c; c.f = f;
    const unsigned int u = c.u;
    const int exp = (int)((u >> 23) & 0xFF) - 127 + 15;
    const unsigned int man = u & 0x7FFFFFu;
    if (exp <= 0) return 0;
    unsigned int base = ((unsigned int)exp << 10) | (man >> 13);
    const unsigned int rem = man & 0x1FFFu;
    base += (rem > 0x1000u) || (rem == 0x1000u && (base & 1u));
    return (unsigned short)base;
}
static float f16_to_f32(unsigned short h) {
    const int exp = (h >> 10) & 0x1F;
    const unsigned int man = h & 0x3FFu;
    if (exp == 0) return 0.f;
    union { unsigned int u; float f; } c;
    c.u = ((unsigned int)(exp - 15 + 127) << 23) | (man << 13);
    return c.f;
}

extern "C" void kernel_launch(void* const* d_in, const int* in_sizes, int n_in,
                              void* d_out, int out_size, void* d_ws, size_t ws_size,
                              hipStream_t stream)
{
    const float* pred = (const float*)d_in[0];
    const float* targ = (const float*)d_in[1];
    float* out = (float*)d_out;

    GW gw;
    {
        double g[7], s = 0.0;
        for (int i = 0; i < 7; ++i) {
            const double c = (double)(i - 3);
            g[i] = exp(-c * c / (2.0 * 1.5 * 1.5));
            s += g[i];
        }
        unsigned short h16[7];
        for (int i = 0; i < 7; ++i) h16[i] = f32_to_f16((float)(g[i] / s));
        // renormalize so the f16 weights sum as close to 1.0 as representable:
        // center tap = round_f16(1 - sum(others)) kills the systematic bias.
        float so = 0.f;
        for (int i = 0; i < 7; ++i) if (i != 3) so += f16_to_f32(h16[i]);
        h16[3] = f32_to_f16(1.0f - so);
        for (int i = 0; i < 7; ++i)
            gw.wh[i] = (unsigned int)h16[i] | ((unsigned int)h16[i] << 16);
    }

    const bool usews = (ws_size >= NBLK * sizeof(float));
    float* partial = usews ? (float*)d_ws : nullptr;
    if (!usews) (void)hipMemsetAsync(d_out, 0, sizeof(float), stream);

    ssim_main_k<<<NBLK, TPB, 0, stream>>>(pred, targ, partial, out, gw);
    ssim_finalize_k<<<1, 256, 0, stream>>>(partial, out, usews ? 1 : 0);
}

// Round 20
// 49.506 us; speedup vs baseline: 6.8119x; 1.0702x over previous
//
#include <hip/hip_runtime.h>
#include <cmath>

#define TPB   128                 // threads per block (2 waves); each thread owns 4 cols
#define TH    16                  // output rows per block tile (22 input rows)
#define WID   512
#define HEI   512
#define NIMG  64
#define NTILE (HEI / TH)          // 32
#define NBLK  (NIMG * NTILE)      // 2048

// LEDGER: R14 = 50.1us (56 VGPR, VALUBusy 51%). Eight latency-hiding
// structures spilled or washed (R2,R3,R9,R13,R15,R16,R17 spill; R8,R19
// wash). R14 shape is the only healthy operating point. R20 = R14 with
// the 0.5x epilogue factors FOLDED INTO THE WEIGHTS: AB-ring weights
// scaled by 2^-1/4 (A squared downstream -> 1/2 A^2), ST-ring weights by
// 2^-1/2 (S linear -> 1/2 S). Epilogue: muct2=A2-B2, ptb2=fS-fT etc.
// directly — 16 fewer f32 ops per V-stage, ~6% of kernel VALU. Zero
// structural change, zero VGPR delta.

typedef _Float16 h2 __attribute__((ext_vector_type(2)));

struct GW { unsigned int wa[7]; unsigned int ws[7]; };  // scaled f16 pairs (lo==hi)

__device__ __forceinline__ h2 pkrtz(float a, float b) {
    return __builtin_bit_cast(h2, __builtin_amdgcn_cvt_pkrtz(a, b));
}
__device__ __forceinline__ h2 fma2(h2 a, h2 b, h2 c) { return __builtin_elementwise_fma(a, b, c); }

// One input-row stage: load row gy (f32), pack (s,d)=(p+t,p-t) per column,
// H-blur with the two scaled weight sets into ring slot SL; when IY>=6
// V-blur + SSIM (f32, no 0.5 factors — folded into weights).
template <int SL>
__device__ __forceinline__ void ssim_stage(
    int IY, int oy0, int m, int c0, int clm, int clp,
    const float* __restrict__ pb, const float* __restrict__ tb,
    const h2 (&wa)[7], const h2 (&ws)[7],
    h2 (&rAB)[7][4], h2 (&rST)[7][4],
    float& acc)
{
    const int gy = oy0 - 3 + IY;
    float pa[12], ta[12];
    if (gy >= 0 && gy < HEI) {
        const float* pr = pb + (size_t)gy * WID;
        const float* tr = tb + (size_t)gy * WID;
        float4 v0 = *(const float4*)(pr + clm);
        float4 v1 = *(const float4*)(pr + c0);
        float4 v2 = *(const float4*)(pr + clp);
        float4 u0 = *(const float4*)(tr + clm);
        float4 u1 = *(const float4*)(tr + c0);
        float4 u2 = *(const float4*)(tr + clp);
        if (m == 0)       { v0 = make_float4(0.f,0.f,0.f,0.f); u0 = make_float4(0.f,0.f,0.f,0.f); }
        if (m == TPB - 1) { v2 = make_float4(0.f,0.f,0.f,0.f); u2 = make_float4(0.f,0.f,0.f,0.f); }
        pa[0]=v0.x; pa[1]=v0.y; pa[2]=v0.z; pa[3]=v0.w;
        pa[4]=v1.x; pa[5]=v1.y; pa[6]=v1.z; pa[7]=v1.w;
        pa[8]=v2.x; pa[9]=v2.y; pa[10]=v2.z; pa[11]=v2.w;
        ta[0]=u0.x; ta[1]=u0.y; ta[2]=u0.z; ta[3]=u0.w;
        ta[4]=u1.x; ta[5]=u1.y; ta[6]=u1.z; ta[7]=u1.w;
        ta[8]=u2.x; ta[9]=u2.y; ta[10]=u2.z; ta[11]=u2.w;
    } else {
#pragma unroll
        for (int k = 0; k < 12; ++k) { pa[k] = 0.f; ta[k] = 0.f; }
    }

    // window col k = image column (c0 - 3 + k); output col c uses k = c..c+6
    h2 sd[10], sq[10];
#pragma unroll
    for (int k = 0; k < 10; ++k) {
        const float s = pa[k + 1] + ta[k + 1];
        const float d = pa[k + 1] - ta[k + 1];
        sd[k] = pkrtz(s, d);        // (s, d) packed per column
        sq[k] = sd[k] * sd[k];      // (s^2, d^2)
    }

    // H-blur: AB ring with wa (2^-1/4-scaled), ST ring with ws (2^-1/2-scaled)
#pragma unroll
    for (int c = 0; c < 4; ++c) {
        h2 ab = wa[0] * sd[c];
        h2 st = ws[0] * sq[c];
#pragma unroll
        for (int i = 1; i < 7; ++i) {
            ab = fma2(wa[i], sd[c + i], ab);
            st = fma2(ws[i], sq[c + i], st);
        }
        rAB[SL][c] = ab;
        rST[SL][c] = st;
    }

    if (IY >= 6) {
        const float C1 = 1e-4f, C2 = 9e-4f;
#pragma unroll
        for (int c = 0; c < 4; ++c) {
            h2 vAB = wa[0] * rAB[(SL + 1) % 7][c];
            h2 vST = ws[0] * rST[(SL + 1) % 7][c];
#pragma unroll
            for (int j = 1; j < 7; ++j) {
                const int sl = (SL + 1 + j) % 7;   // compile-time
                vAB = fma2(wa[j], rAB[sl][c], vAB);
                vST = fma2(ws[j], rST[sl][c], vST);
            }
            // weights folded: A=2^-1/2 blur2(s) -> A2 = 1/2 blur2(s)^2;
            // fS = 1/2 blur2(s^2). All 0.5 factors implicit.
            const float fA = (float)vAB[0], fB = (float)vAB[1];
            const float fS = (float)vST[0], fT = (float)vST[1];
            const float A2 = fA * fA, B2 = fB * fB;
            const float muct2 = A2 - B2;        // 2*mu_p*mu_t
            const float muss  = A2 + B2;        // mu_p^2 + mu_t^2
            const float ptb2  = fS - fT;        // 2*blur(p*t)
            const float ssb   = fS + fT;        // blur(p^2 + t^2)
            const float num = (muct2 + C1) * (ptb2 - muct2 + C2);
            const float den = (muss + C1) * (ssb - muss + C2);
            acc += num * __builtin_amdgcn_rcpf(den);
        }
    }
}

__global__ __launch_bounds__(TPB, 4)
void ssim_main_k(const float* __restrict__ pred,
                 const float* __restrict__ targ,
                 float* __restrict__ partial,   // NBLK floats (d_ws), or null
                 float* __restrict__ outacc,    // fallback atomic accumulator
                 GW gw)
{
    const int m    = threadIdx.x;
    const int bid  = blockIdx.x;
    const int img  = bid >> 5;            // NTILE == 32
    const int tile = bid & (NTILE - 1);
    const int oy0  = tile * TH;

    h2 wa[7], ws[7];
#pragma unroll
    for (int j = 0; j < 7; ++j) {
        wa[j] = __builtin_bit_cast(h2, gw.wa[j]);
        ws[j] = __builtin_bit_cast(h2, gw.ws[j]);
    }

    const size_t ioff = (size_t)img * (WID * HEI);
    const float* pb = pred + ioff;
    const float* tb = targ + ioff;

    const int c0  = 4 * m;
    const int clm = (m == 0) ? 0 : (c0 - 4);          // clamped (value zeroed)
    const int clp = (m == TPB - 1) ? c0 : (c0 + 4);   // clamped (value zeroed)

    h2 rAB[7][4], rST[7][4];    // ring: [slot][col], (A,B) and (S,T) packed
    float acc = 0.f;

    // 22 input rows = 3*7 + 1; groups of 7 so ring slot == IY % 7 is static
    for (int it = 0; it < 3; ++it) {
        const int base = it * 7;
        ssim_stage<0>(base + 0, oy0, m, c0, clm, clp, pb, tb, wa, ws, rAB, rST, acc);
        ssim_stage<1>(base + 1, oy0, m, c0, clm, clp, pb, tb, wa, ws, rAB, rST, acc);
        ssim_stage<2>(base + 2, oy0, m, c0, clm, clp, pb, tb, wa, ws, rAB, rST, acc);
        ssim_stage<3>(base + 3, oy0, m, c0, clm, clp, pb, tb, wa, ws, rAB, rST, acc);
        ssim_stage<4>(base + 4, oy0, m, c0, clm, clp, pb, tb, wa, ws, rAB, rST, acc);
        ssim_stage<5>(base + 5, oy0, m, c0, clm, clp, pb, tb, wa, ws, rAB, rST, acc);
        ssim_stage<6>(base + 6, oy0, m, c0, clm, clp, pb, tb, wa, ws, rAB, rST, acc);
    }
    ssim_stage<0>(21, oy0, m, c0, clm, clp, pb, tb, wa, ws, rAB, rST, acc);

    // block reduction: wave shfl tree, then cross-wave via LDS
#pragma unroll
    for (int off = 32; off > 0; off >>= 1)
        acc += __shfl_down(acc, off, 64);
    __shared__ float wpart[TPB / 64];
    if ((m & 63) == 0) wpart[m >> 6] = acc;
    __syncthreads();
    if (m == 0) {
        const float tot = wpart[0] + wpart[1];
        if (partial) partial[bid] = tot;
        else atomicAdd(outacc, tot);
    }
}

__global__ void ssim_finalize_k(const float* __restrict__ partial,
                                float* __restrict__ out, int usews)
{
    const float invN = 1.0f / (float)((size_t)NIMG * WID * HEI);
    if (usews) {
        float s = 0.f;
        for (int i = threadIdx.x; i < NBLK; i += 256) s += partial[i];
#pragma unroll
        for (int off = 32; off > 0; off >>= 1) s += __shfl_down(s, off, 64);
        __shared__ float wp[4];
        if ((threadIdx.x & 63) == 0) wp[threadIdx.x >> 6] = s;
        __syncthreads();
        if (threadIdx.x == 0) out[0] = 1.0f - (wp[0] + wp[1] + wp[2] + wp[3]) * invN;
    } else {
        if (threadIdx.x == 0) out[0] = 1.0f - out[0] * invN;
    }
}

// host f32 -> f16 bits, round-to-nearest-even (weights are normal, positive)
static unsigned short f32_to_f16(float f) {
    union { float f; unsigned int u; } c; c.f = f;
    const unsigned int u = c.u;
    const int exp = (int)((u >> 23) & 0xFF) - 127 + 15;
    const unsigned int man = u & 0x7FFFFFu;
    if (exp <= 0) return 0;
    unsigned int base = ((unsigned int)exp << 10) | (man >> 13);
    const unsigned int rem = man & 0x1FFFu;
    base += (rem > 0x1000u) || (rem == 0x1000u && (base & 1u));
    return (unsigned short)base;
}
static float f16_to_f32(unsigned short h) {
    const int exp = (h >> 10) & 0x1F;
    const unsigned int man = h & 0x3FFu;
    if (exp == 0) return 0.f;
    union { unsigned int u; float f; } c;
    c.u = ((unsigned int)(exp - 15 + 127) << 23) | (man << 13);
    return c.f;
}
// Build 7 scaled f16 taps whose SUM is as close to (scale) as representable:
// round each, then set the center tap to round(target - sum(others)).
static void build_taps(const double* gnorm, double scale, unsigned int* outw) {
    unsigned short h16[7];
    for (int i = 0; i < 7; ++i) h16[i] = f32_to_f16((float)(gnorm[i] * scale));
    float so = 0.f;
    for (int i = 0; i < 7; ++i) if (i != 3) so += f16_to_f32(h16[i]);
    h16[3] = f32_to_f16((float)scale - so);
    for (int i = 0; i < 7; ++i)
        outw[i] = (unsigned int)h16[i] | ((unsigned int)h16[i] << 16);
}

extern "C" void kernel_launch(void* const* d_in, const int* in_sizes, int n_in,
                              void* d_out, int out_size, void* d_ws, size_t ws_size,
                              hipStream_t stream)
{
    const float* pred = (const float*)d_in[0];
    const float* targ = (const float*)d_in[1];
    float* out = (float*)d_out;

    GW gw;
    {
        double g[7], s = 0.0;
        for (int i = 0; i < 7; ++i) {
            const double c = (double)(i - 3);
            g[i] = exp(-c * c / (2.0 * 1.5 * 1.5));
            s += g[i];
        }
        for (int i = 0; i < 7; ++i) g[i] /= s;
        build_taps(g, 0.8408964152537145, gw.wa);   // 2^-1/4: AB ring (A squared -> 1/2)
        build_taps(g, 0.7071067811865476, gw.ws);   // 2^-1/2: ST ring (S linear -> 1/2)
    }

    const bool usews = (ws_size >= NBLK * sizeof(float));
    float* partial = usews ? (float*)d_ws : nullptr;
    if (!usews) (void)hipMemsetAsync(d_out, 0, sizeof(float), stream);

    ssim_main_k<<<NBLK, TPB, 0, stream>>>(pred, targ, partial, out, gw);
    ssim_finalize_k<<<1, 256, 0, stream>>>(partial, out, usews ? 1 : 0);
}